// Round 9
// baseline (1308.902 us; speedup 1.0000x reference)
//
#include <hip/hip_runtime.h>

#define NN 100000
#define NE 1600000
#define NBK 512   // dst buckets
#define BSZ 196   // nodes per bucket (512*196 = 100352 >= NN)
#define NCH 8     // src chunks
#define CSZ 12500 // nodes per src chunk
#define NBIN 4096 // NBK*NCH
#define EBLK 256  // edge blocks; 6250 edges each

typedef __attribute__((ext_vector_type(8))) short short8;
typedef __attribute__((ext_vector_type(4))) float floatx4;

__device__ __forceinline__ unsigned short f2bf(float f) {
  unsigned u = __float_as_uint(f);
  u += 0x7fffu + ((u >> 16) & 1u);  // RNE
  return (unsigned short)(u >> 16);
}
__device__ __forceinline__ float bf2f(unsigned short b) {
  return __uint_as_float(((unsigned)b) << 16);
}

// ---------------------------------------------------------------------------
// Convert the 4 weight matrices (each 64x64 f32 row-major) to bf16.
__global__ __launch_bounds__(256) void k_cvtW(const float* __restrict__ W1,
                                              const float* __restrict__ W2,
                                              const float* __restrict__ W3,
                                              const float* __restrict__ W4,
                                              unsigned short* __restrict__ Wb) {
  int i = blockIdx.x * 256 + threadIdx.x;  // 16*256 = 4096 exact
  Wb[i] = f2bf(W1[i]);
  Wb[4096 + i] = f2bf(W2[i]);
  Wb[8192 + i] = f2bf(W3[i]);
  Wb[12288 + i] = f2bf(W4[i]);
}

// x (f32) -> bf16 copy for neighbor reads (self term keeps f32 path).
__global__ __launch_bounds__(256) void k_cvtX(const float* __restrict__ x,
                                              unsigned short* __restrict__ xb) {
  int i = blockIdx.x * 256 + threadIdx.x;  // over NN*16 float4s (6250 blocks)
  float4 v = ((const float4*)x)[i];
  ushort4 u;
  u.x = f2bf(v.x); u.y = f2bf(v.y); u.z = f2bf(v.z); u.w = f2bf(v.w);
  ((ushort4*)xb)[i] = u;
}

// ---------------------------------------------------------------------------
// 2D bin = (d/BSZ)*NCH + s/CSZ. Pass 1: per-(block,bin) histogram (LDS only).
__global__ __launch_bounds__(256) void k_phist(const int* __restrict__ src,
                                               const int* __restrict__ dst,
                                               int* __restrict__ blockHist) {
  __shared__ int h[NBIN];
  for (int i = threadIdx.x; i < NBIN; i += 256) h[i] = 0;
  __syncthreads();
  int lo = blockIdx.x * 6250, hi = lo + 6250;
  for (int e = lo + threadIdx.x; e < hi; e += 256) {
    int bin = (dst[e] / BSZ) * NCH + src[e] / CSZ;
    atomicAdd(&h[bin], 1);
  }
  __syncthreads();
  for (int i = threadIdx.x; i < NBIN; i += 256)
    blockHist[i * EBLK + blockIdx.x] = h[i];
}

// Pass 2: per-bin exclusive scan over the EBLK block counts.
__global__ __launch_bounds__(256) void k_colscan(const int* __restrict__ blockHist,
                                                 int* __restrict__ offsL,
                                                 int* __restrict__ colTot) {
  __shared__ int sh[256];
  int bin = blockIdx.x, t = threadIdx.x;
  int v = blockHist[bin * EBLK + t];
  sh[t] = v;
  __syncthreads();
  for (int off = 1; off < 256; off <<= 1) {
    int u = (t >= off) ? sh[t - off] : 0;
    __syncthreads();
    sh[t] += u;
    __syncthreads();
  }
  offsL[bin * EBLK + t] = sh[t] - v;
  if (t == 255) colTot[bin] = sh[255];
}

// Pass 3: exclusive scan of NBIN bin totals -> bin bases (1 block, 4/thread).
__global__ __launch_bounds__(1024) void k_basescan(const int* __restrict__ colTot,
                                                   int* __restrict__ base) {
  __shared__ int sh[1024];
  int t = threadIdx.x;
  int4 v = ((const int4*)colTot)[t];
  int s1 = v.x + v.y, s2 = s1 + v.z, tot = s2 + v.w;
  sh[t] = tot;
  __syncthreads();
  for (int off = 1; off < 1024; off <<= 1) {
    int u = (t >= off) ? sh[t - off] : 0;
    __syncthreads();
    sh[t] += u;
    __syncthreads();
  }
  int pre = sh[t] - tot;
  base[4 * t] = pre;
  base[4 * t + 1] = pre + v.x;
  base[4 * t + 2] = pre + s1;
  base[4 * t + 3] = pre + s2;
  if (t == 1023) base[NBIN] = pre + tot;
}

// Pass 4: scatter packed edge words into bin-partitioned array (LDS ranks).
// word = (s % CSZ) << 8 | (d % BSZ)   [14 + 8 bits]
__global__ __launch_bounds__(256) void k_escat(const int* __restrict__ src,
                                               const int* __restrict__ dst,
                                               const int* __restrict__ offsL,
                                               const int* __restrict__ base,
                                               int* __restrict__ edm) {
  __shared__ int h[NBIN];
  for (int i = threadIdx.x; i < NBIN; i += 256) h[i] = 0;
  __syncthreads();
  int lo = blockIdx.x * 6250, hi = lo + 6250;
  for (int e = lo + threadIdx.x; e < hi; e += 256) {
    int s = src[e], d = dst[e];
    int bucket = d / BSZ, chunk = s / CSZ;
    int bin = bucket * NCH + chunk;
    int r = atomicAdd(&h[bin], 1);
    edm[base[bin] + offsL[bin * EBLK + blockIdx.x] + r] =
        ((s - chunk * CSZ) << 8) | (d - bucket * BSZ);
  }
}

// ---------------------------------------------------------------------------
// Gather with LDS accumulation: one block per dst-bucket; f32 accum tile
// [BSZ][69] in LDS (pad 69 == 1 mod 4 spreads ds_add bank classes).
// Edges processed chunk-by-chunk: blocks on an XCD walk chunks in the same
// order, keeping the 1.6 MB bf16 src-chunk L2-resident (reuse capture).
// 16 lanes per edge, ushort4 (4 feats) per lane.
// MODE 0: neighbors from xb(=x bf16), self from xf (f32), pre=identity.
// MODE 1: neighbors+self from xb(=h2 bf16), pre=BN1 affine.
template <int MODE>
__global__ __launch_bounds__(512) void k_gather_lds(
    const float* __restrict__ xf, const unsigned short* __restrict__ xb,
    const int* __restrict__ edm, const int* __restrict__ base,
    const float* __restrict__ eps, const float* __restrict__ AB,
    unsigned short* __restrict__ agg) {
  __shared__ float acc[BSZ * 69];
  const int bucket = blockIdx.x;
  const int tid = threadIdx.x;
  for (int i = tid; i < BSZ * 69; i += 512) acc[i] = 0.0f;
  __syncthreads();
  const int g = tid >> 4, l16 = tid & 15;
  float4 A4 = {1.f, 1.f, 1.f, 1.f}, B4 = {0.f, 0.f, 0.f, 0.f};
  if (MODE) { A4 = ((const float4*)AB)[l16]; B4 = ((const float4*)(AB + 64))[l16]; }
#pragma unroll 1
  for (int chunk = 0; chunk < NCH; chunk++) {
    const int lo = base[bucket * NCH + chunk], hi = base[bucket * NCH + chunk + 1];
    const int sb = chunk * CSZ;
    for (int e = lo + g; e < hi; e += 32) {
      int w = edm[e];
      int dl = w & 255;
      int s = sb + (w >> 8);
      ushort4 u = *(const ushort4*)(xb + s * 64 + l16 * 4);
      float v0 = bf2f(u.x), v1 = bf2f(u.y), v2 = bf2f(u.z), v3 = bf2f(u.w);
      if (MODE) {
        v0 = fmaf(v0, A4.x, B4.x); v1 = fmaf(v1, A4.y, B4.y);
        v2 = fmaf(v2, A4.z, B4.z); v3 = fmaf(v3, A4.w, B4.w);
      }
      float* p = acc + dl * 69 + l16 * 4;
      atomicAdd(p + 0, v0);
      atomicAdd(p + 1, v1);
      atomicAdd(p + 2, v2);
      atomicAdd(p + 3, v3);
    }
  }
  __syncthreads();
  const float es = 1.0f + eps[0];
  for (int i = tid; i < BSZ * 64; i += 512) {
    int nl = i >> 6, f = i & 63;
    int n = bucket * BSZ + nl;
    if (n < NN) {
      float self;
      if (MODE) self = fmaf(bf2f(xb[n * 64 + f]), AB[f], AB[64 + f]);
      else self = xf[n * 64 + f];
      agg[n * 64 + f] = f2bf(acc[nl * 69 + f] + es * self);
    }
  }
}

// ---------------------------------------------------------------------------
// h2 = relu(relu(agg@Wa+ba)@Wb+bb) via bf16 MFMA 16x16x32; BN stats to f64.
__global__ __launch_bounds__(256) void k_mlp_mfma(
    const unsigned short* __restrict__ agg, const unsigned short* __restrict__ Wab,
    const float* __restrict__ ba, const float* __restrict__ bb,
    unsigned short* __restrict__ h2, double* __restrict__ stats) {
  const int l = threadIdx.x & 63;
  const int wv = threadIdx.x >> 6;
  const int l16 = l & 15, quad = l >> 4;

  short8 wfa[4][2], wfb[4][2];
#pragma unroll
  for (int c = 0; c < 4; c++)
#pragma unroll
    for (int t = 0; t < 2; t++)
#pragma unroll
      for (int j = 0; j < 8; j++) {
        int k = t * 32 + quad * 8 + j, nn = c * 16 + l16;
        wfa[c][t][j] = (short)Wab[k * 64 + nn];
        wfb[c][t][j] = (short)Wab[4096 + k * 64 + nn];
      }
  float bia[4], bib[4];
#pragma unroll
  for (int c = 0; c < 4; c++) { bia[c] = ba[c * 16 + l16]; bib[c] = bb[c * 16 + l16]; }

  __shared__ float Hs[4][16][68];
  __shared__ float sS[4][64], sQ[4][64];
  float ssum[4] = {0, 0, 0, 0}, ssq[4] = {0, 0, 0, 0};

  const int totw = gridDim.x * 4;
  for (int tile = blockIdx.x * 4 + wv; tile < NN / 16; tile += totw) {
    const int r0 = tile * 16;
    const unsigned short* ap = agg + (r0 + l16) * 64 + quad * 8;
    short8 a0 = *(const short8*)ap;
    short8 a1 = *(const short8*)(ap + 32);
#pragma unroll
    for (int c = 0; c < 4; c++) {
      floatx4 acc = {0.f, 0.f, 0.f, 0.f};
      acc = __builtin_amdgcn_mfma_f32_16x16x32_bf16(a0, wfa[c][0], acc, 0, 0, 0);
      acc = __builtin_amdgcn_mfma_f32_16x16x32_bf16(a1, wfa[c][1], acc, 0, 0, 0);
#pragma unroll
      for (int r = 0; r < 4; r++)
        Hs[wv][quad * 4 + r][c * 16 + l16] = fmaxf(acc[r] + bia[c], 0.0f);
    }
    short8 a20, a21;
#pragma unroll
    for (int j = 0; j < 8; j++) {
      a20[j] = (short)f2bf(Hs[wv][l16][quad * 8 + j]);
      a21[j] = (short)f2bf(Hs[wv][l16][32 + quad * 8 + j]);
    }
#pragma unroll
    for (int c = 0; c < 4; c++) {
      floatx4 acc = {0.f, 0.f, 0.f, 0.f};
      acc = __builtin_amdgcn_mfma_f32_16x16x32_bf16(a20, wfb[c][0], acc, 0, 0, 0);
      acc = __builtin_amdgcn_mfma_f32_16x16x32_bf16(a21, wfb[c][1], acc, 0, 0, 0);
#pragma unroll
      for (int r = 0; r < 4; r++) {
        float v = fmaxf(acc[r] + bib[c], 0.0f);
        h2[(r0 + quad * 4 + r) * 64 + c * 16 + l16] = f2bf(v);
        ssum[c] += v;
        ssq[c] += v * v;
      }
    }
  }
#pragma unroll
  for (int c = 0; c < 4; c++) {
    float s = ssum[c], q = ssq[c];
    s += __shfl_xor(s, 16, 64); s += __shfl_xor(s, 32, 64);
    q += __shfl_xor(q, 16, 64); q += __shfl_xor(q, 32, 64);
    if (quad == 0) { sS[wv][c * 16 + l16] = s; sQ[wv][c * 16 + l16] = q; }
  }
  __syncthreads();
  if (threadIdx.x < 64) {
    int ff = threadIdx.x;
    float s = sS[0][ff] + sS[1][ff] + sS[2][ff] + sS[3][ff];
    float q = sQ[0][ff] + sQ[1][ff] + sQ[2][ff] + sQ[3][ff];
    unsafeAtomicAdd(&stats[ff], (double)s);
    unsafeAtomicAdd(&stats[64 + ff], (double)q);
  }
}

// ---------------------------------------------------------------------------
// stats -> per-feature affine A (scale), B (shift): out = h*A + B
__global__ void k_bnfin(const double* __restrict__ stats, const float* __restrict__ gam,
                        const float* __restrict__ bet, float* __restrict__ AB) {
  int f = threadIdx.x;  // 64 threads
  double mean = stats[f] * (1.0 / NN);
  double var = stats[64 + f] * (1.0 / NN) - mean * mean;
  if (var < 0.0) var = 0.0;
  float rstd = (float)(1.0 / sqrt(var + 1e-5));
  float A = gam[f] * rstd;
  float B = bet[f] - (float)mean * A;
  AB[f] = A;
  AB[64 + f] = B;
}

// ---------------------------------------------------------------------------
// h = BN2(h2); out[0:N*64] = h; out[N*64:] = log_softmax(h) per row.
__global__ __launch_bounds__(256) void k_out(const unsigned short* __restrict__ h2,
                                             const float* __restrict__ AB,
                                             float* __restrict__ out) {
  int f = threadIdx.x & 63;
  int n = blockIdx.x * 4 + (threadIdx.x >> 6);  // 25000*4 = NN exact
  float v = bf2f(h2[n * 64 + f]);
  float h = fmaf(v, AB[f], AB[64 + f]);
  float m = h;
#pragma unroll
  for (int off = 32; off; off >>= 1) m = fmaxf(m, __shfl_xor(m, off, 64));
  float e = expf(h - m);
  float ssum = e;
#pragma unroll
  for (int off = 32; off; off >>= 1) ssum += __shfl_xor(ssum, off, 64);
  float lsm = (h - m) - logf(ssum);
  out[n * 64 + f] = h;
  out[(size_t)NN * 64 + n * 64 + f] = lsm;
}

// ---------------------------------------------------------------------------
extern "C" void kernel_launch(void* const* d_in, const int* in_sizes, int n_in,
                              void* d_out, int out_size, void* d_ws, size_t ws_size,
                              hipStream_t stream) {
  const float* x = (const float*)d_in[0];
  const int* ei = (const int*)d_in[1];  // [2, E] as int32
  const float* W1 = (const float*)d_in[2];
  const float* b1 = (const float*)d_in[3];
  const float* W2 = (const float*)d_in[4];
  const float* b2 = (const float*)d_in[5];
  const float* g1 = (const float*)d_in[6];
  const float* bt1 = (const float*)d_in[7];
  const float* e1 = (const float*)d_in[8];
  const float* W3 = (const float*)d_in[9];
  const float* b3 = (const float*)d_in[10];
  const float* W4 = (const float*)d_in[11];
  const float* b4 = (const float*)d_in[12];
  const float* g2 = (const float*)d_in[13];
  const float* bt2 = (const float*)d_in[14];
  const float* e2 = (const float*)d_in[15];
  const int* src = ei;
  const int* dst = ei + NE;

  char* ws = (char*)d_ws;
  unsigned short* aggb = (unsigned short*)(ws);             // 12.8 MB
  unsigned short* h2b = (unsigned short*)(ws + 12800000);   // 12.8 MB
  unsigned short* xbf = (unsigned short*)(ws + 25600000);   // 12.8 MB (x as bf16)
  int* edm = (int*)(ws + 38400000);                         // 6.4 MB packed edges
  int* blockHist = (int*)(ws + 44800000);                   // 4096*256 = 4 MB
  int* offsL = (int*)(ws + 48994304);                       // 4 MB
  int* colTot = (int*)(ws + 53188608);                      // 16 KB
  int* base = (int*)(ws + 53204992);                        // 4097 ints
  double* st1 = (double*)(ws + 53221504);                   // 1 KB
  double* st2 = (double*)(ws + 53222528);                   // 1 KB
  float* AB1 = (float*)(ws + 53223552);                     // 512 B
  float* AB2 = (float*)(ws + 53224064);                     // 512 B
  unsigned short* Wbb = (unsigned short*)(ws + 53224576);   // 32 KB
  float* out = (float*)d_out;

  hipMemsetAsync(ws + 53221504, 0, 2048, stream);  // zero st1+st2

  k_cvtW<<<16, 256, 0, stream>>>(W1, W2, W3, W4, Wbb);
  k_cvtX<<<6250, 256, 0, stream>>>(x, xbf);

  // --- 2D (dst-bucket x src-chunk) edge partition; no global atomics ---
  k_phist<<<EBLK, 256, 0, stream>>>(src, dst, blockHist);
  k_colscan<<<NBIN, 256, 0, stream>>>(blockHist, offsL, colTot);
  k_basescan<<<1, 1024, 0, stream>>>(colTot, base);
  k_escat<<<EBLK, 256, 0, stream>>>(src, dst, offsL, base, edm);

  // --- Layer 1 ---
  k_gather_lds<0><<<NBK, 512, 0, stream>>>(x, xbf, edm, base, e1, nullptr, aggb);
  k_mlp_mfma<<<391, 256, 0, stream>>>(aggb, Wbb, b1, b2, h2b, st1);
  k_bnfin<<<1, 64, 0, stream>>>(st1, g1, bt1, AB1);
  // --- Layer 2 (BN1-apply fused into the gather) ---
  k_gather_lds<1><<<NBK, 512, 0, stream>>>(nullptr, h2b, edm, base, e2, AB1, aggb);
  k_mlp_mfma<<<391, 256, 0, stream>>>(aggb, Wbb + 8192, b3, b4, h2b, st2);
  k_bnfin<<<1, 64, 0, stream>>>(st2, g2, bt2, AB2);
  // --- Epilogue: BN2 + log_softmax ---
  k_out<<<NN / 4, 256, 0, stream>>>(h2b, AB2, out);
}